// Round 1
// baseline (797.760 us; speedup 1.0000x reference)
//
#include <hip/hip_runtime.h>
#include <math.h>

#define TSEQ 4096
#define NQH 16
#define NKVH 8
#define HD 128
#define WINSZ 1024
#define QT 128      // q rows per block (4 waves x 2 stripes x 16)
#define KT 64       // kv rows per tile

#define KSTR 136    // sK row stride in halves (128 + 8 pad)
#define VSTR 72     // sV row stride in halves (64 + 8 pad)
#define PSTR 72     // sP row stride in halves

#define LOG2E 1.44269504088896f

typedef _Float16 h8 __attribute__((ext_vector_type(8)));
typedef _Float16 h4 __attribute__((ext_vector_type(4)));
typedef float    f4 __attribute__((ext_vector_type(4)));

// Flash sliding-window attention, GQA 16q/8kv, d=128, window=1024 (incl. self).
// MFMA 16x16x32 f16, SWAPPED operands: S' = mfma(K, Q) so D col=lane&15 = q row.
// Each lane owns one full q-row (q=ln): softmax reduce = serial + shfl_xor(16,32);
// P write to sP is contiguous h4; PV also swapped: O^T = mfma(V^T, P), so the
// O accumulator is q=ln-major and the rescale factor is lane-uniform.
// NOTE: __launch_bounds__(256,2) — (256,3) forces VGPR cap 84 -> ~1.1 GB spill
// traffic per launch (prev session R2: WRITE_SIZE 131 MB -> 1.255 GB, dur 2x).
__global__ __launch_bounds__(256, 2)
void fa_swa_kernel(const float* __restrict__ Qg, const float* __restrict__ Kg,
                   const float* __restrict__ Vg, float* __restrict__ Og) {
  __shared__ _Float16 sK[KT * KSTR];        // [s][dd] fp16        17408 B
  __shared__ _Float16 sV[HD * VSTR];        // [dd][s] fp16 (T)    18432 B
  __shared__ _Float16 sP[4][16 * PSTR];     // per-wave P buffer    9216 B -> 44 KB

  const int tid  = threadIdx.x;
  const int w    = tid >> 6;
  const int lane = tid & 63;
  const int quad = lane >> 4;
  const int ln   = lane & 15;

  const int qt = blockIdx.x;
  const int h  = blockIdx.y;
  const int bz = blockIdx.z;
  const int hk = h >> 1;
  const int q0 = qt * QT;

  // ---- Q fragments in registers (A/B-layout), fp32 -> fp16, pre-scaled by
  // log2(e) so softmax runs directly on v_exp_f32 (exp2 domain) ----
  h8 qf[2][4];
  #pragma unroll
  for (int r = 0; r < 2; ++r) {
    const int qg = q0 + w * 32 + r * 16 + ln;
    const float* qp = Qg + ((size_t)((size_t)bz * TSEQ + qg) * NQH + h) * HD + quad * 8;
    #pragma unroll
    for (int ks = 0; ks < 4; ++ks) {
      f4 a = *(const f4*)(qp + ks * 32);
      f4 b = *(const f4*)(qp + ks * 32 + 4);
      h8 qv;
      qv[0] = (_Float16)(a[0] * LOG2E); qv[1] = (_Float16)(a[1] * LOG2E);
      qv[2] = (_Float16)(a[2] * LOG2E); qv[3] = (_Float16)(a[3] * LOG2E);
      qv[4] = (_Float16)(b[0] * LOG2E); qv[5] = (_Float16)(b[1] * LOG2E);
      qv[6] = (_Float16)(b[2] * LOG2E); qv[7] = (_Float16)(b[3] * LOG2E);
      qf[r][ks] = qv;
    }
  }

  f4 Oacc[2][8];
  #pragma unroll
  for (int r = 0; r < 2; ++r)
    #pragma unroll
    for (int c = 0; c < 8; ++c)
      Oacc[r][c] = (f4){0.f, 0.f, 0.f, 0.f};

  // per-lane running softmax state for q = ln (one row per lane, per stripe)
  float mrow[2] = {-INFINITY, -INFINITY};
  float lrow[2] = {0.f, 0.f};

  int s_begin = q0 - WINSZ; if (s_begin < 0) s_begin = 0;   // multiple of 64
  const int s_end = q0 + QT;

  const float* kbase = Kg + ((size_t)((size_t)bz * TSEQ) * NKVH + hk) * HD;
  const float* vbase = Vg + ((size_t)((size_t)bz * TSEQ) * NKVH + hk) * HD;

  for (int s0 = s_begin; s0 < s_end; s0 += KT) {
    __syncthreads();   // protect sK/sV from previous iteration's readers

    // ---- stage K tile: sK[s][dd], coalesced f4 loads ----
    {
      const float* kp = kbase + (size_t)s0 * (NKVH * HD);
      #pragma unroll
      for (int i = 0; i < 8; ++i) {
        int e   = tid + 256 * i;     // float4 index within 64x128 tile
        int row = e >> 5;
        int c4  = (e & 31) * 4;
        f4 x = *(const f4*)(kp + (size_t)row * (NKVH * HD) + c4);
        h4 hv;
        hv[0] = (_Float16)x[0]; hv[1] = (_Float16)x[1];
        hv[2] = (_Float16)x[2]; hv[3] = (_Float16)x[3];
        *(h4*)(&sK[row * KSTR + c4]) = hv;
      }
    }
    // ---- stage V tile transposed: sV[dd][s] ----
    {
      const int srow = tid & 63;
      const int dd0  = (tid >> 6) * 32;
      const float* vp = vbase + (size_t)(s0 + srow) * (NKVH * HD) + dd0;
      #pragma unroll
      for (int f = 0; f < 8; ++f) {
        f4 x = *(const f4*)(vp + f * 4);
        #pragma unroll
        for (int c = 0; c < 4; ++c)
          sV[(dd0 + f * 4 + c) * VSTR + srow] = (_Float16)x[c];
      }
    }
    __syncthreads();

    // ---- per-stripe compute: dq = stripe_base - s0 (wave-uniform) ----
    const int dq0 = q0 + w * 32 - s0;
    #pragma unroll
    for (int r = 0; r < 2; ++r) {
      const int dq = dq0 + r * 16;
      if (dq < 0 || dq > 1072) continue;   // wave-uniform branch

      // S' = K Q^T (64 keys x 16 q). Lane holds q=ln, keys ct*16+quad*4+g.
      f4 S[4];
      #pragma unroll
      for (int ct = 0; ct < 4; ++ct) {
        f4 acc = (f4){0.f, 0.f, 0.f, 0.f};
        #pragma unroll
        for (int ks = 0; ks < 4; ++ks) {
          h8 kb = *(const h8*)(&sK[(ct * 16 + ln) * KSTR + quad * 8 + ks * 32]);
          acc = __builtin_amdgcn_mfma_f32_16x16x32_f16(kb, qf[r][ks], acc, 0, 0, 0);
        }
        S[ct] = acc;
      }

      // mask only boundary tiles (uniform branch); interior tiles skip entirely
      if (dq < 64 || dq > 1008) {
        const int e = dq + ln - quad * 4;   // q - key = e - ct*16 - g
        #pragma unroll
        for (int ct = 0; ct < 4; ++ct) {
          const int base = e - ct * 16;
          #pragma unroll
          for (int g = 0; g < 4; ++g)
            if ((unsigned)(base - g) > 1023u) S[ct][g] = -INFINITY;
        }
      }

      // ---- online softmax: per-lane serial reduce + 2 shfl_xor ----
      float m = -INFINITY;
      #pragma unroll
      for (int ct = 0; ct < 4; ++ct) {
        m = fmaxf(m, fmaxf(fmaxf(S[ct][0], S[ct][1]), fmaxf(S[ct][2], S[ct][3])));
      }
      m = fmaxf(m, __shfl_xor(m, 16));
      m = fmaxf(m, __shfl_xor(m, 32));
      const float mn = fmaxf(mrow[r], m);
      const bool dead = (mn == -INFINITY);
      const float al = dead ? 1.f : __builtin_amdgcn_exp2f(mrow[r] - mn);
      mrow[r] = mn;

      float ps = 0.f;
      #pragma unroll
      for (int ct = 0; ct < 4; ++ct)
        #pragma unroll
        for (int g = 0; g < 4; ++g) {
          float p = dead ? 0.f : __builtin_amdgcn_exp2f(S[ct][g] - mn);
          S[ct][g] = p;
          ps += p;
        }
      ps += __shfl_xor(ps, 16);
      ps += __shfl_xor(ps, 32);
      lrow[r] = lrow[r] * al + ps;

      // rescale O (al is lane-uniform across all 32 elements)
      #pragma unroll
      for (int ct = 0; ct < 8; ++ct)
        #pragma unroll
        for (int g = 0; g < 4; ++g)
          Oacc[r][ct][g] *= al;

      // ---- P -> LDS (contiguous h4 writes) -> A/B-layout, PV MFMA ----
      __asm__ volatile("s_waitcnt lgkmcnt(0)" ::: "memory");  // prior pa reads retired
      #pragma unroll
      for (int ct = 0; ct < 4; ++ct) {
        h4 pv;
        pv[0] = (_Float16)S[ct][0]; pv[1] = (_Float16)S[ct][1];
        pv[2] = (_Float16)S[ct][2]; pv[3] = (_Float16)S[ct][3];
        *(h4*)(&sP[w][ln * PSTR + ct * 16 + quad * 4]) = pv;
      }
      __asm__ volatile("s_waitcnt lgkmcnt(0)" ::: "memory");  // wave-private RAW

      // O^T += V^T P^T : A = V^T fragment (m=d), B = P fragment (n=q=ln)
      #pragma unroll
      for (int ks = 0; ks < 2; ++ks) {
        h8 pa = *(const h8*)(&sP[w][ln * PSTR + quad * 8 + ks * 32]);
        #pragma unroll
        for (int ct = 0; ct < 8; ++ct) {
          h8 vb = *(const h8*)(&sV[(ct * 16 + ln) * VSTR + quad * 8 + ks * 32]);
          Oacc[r][ct] = __builtin_amdgcn_mfma_f32_16x16x32_f16(vb, pa, Oacc[r][ct], 0, 0, 0);
        }
      }
    }
  }

  // ---- epilogue: O / l, vectorized f4 stores (q = ln, d = ct*16+quad*4+g) ----
  #pragma unroll
  for (int r = 0; r < 2; ++r) {
    const int qg = q0 + w * 32 + r * 16 + ln;
    const float inv = 1.f / lrow[r];
    float* op = Og + ((size_t)((size_t)bz * TSEQ + qg) * NQH + h) * HD + quad * 4;
    #pragma unroll
    for (int ct = 0; ct < 8; ++ct) {
      f4 o;
      o[0] = Oacc[r][ct][0] * inv; o[1] = Oacc[r][ct][1] * inv;
      o[2] = Oacc[r][ct][2] * inv; o[3] = Oacc[r][ct][3] * inv;
      *(f4*)(op + ct * 16) = o;
    }
  }
}

extern "C" void kernel_launch(void* const* d_in, const int* in_sizes, int n_in,
                              void* d_out, int out_size, void* d_ws, size_t ws_size,
                              hipStream_t stream) {
  const float* Q = (const float*)d_in[0];
  const float* K = (const float*)d_in[1];
  const float* V = (const float*)d_in[2];
  float* O = (float*)d_out;
  const int batch = in_sizes[0] / (TSEQ * NQH * HD);   // 4
  dim3 grid(TSEQ / QT, NQH, batch);
  fa_swa_kernel<<<grid, 256, 0, stream>>>(Q, K, V, O);
}

// Round 2
// 568.233 us; speedup vs baseline: 1.4039x; 1.4039x over previous
//
#include <hip/hip_runtime.h>
#include <math.h>

#define TSEQ 4096
#define NQH 16
#define NKVH 8
#define HD 128
#define WINSZ 1024
#define QT 128      // q rows per block (4 waves x 2 stripes x 16)
#define KT 64       // kv rows per tile

#define KSTR 136    // sK row stride in halves (128 + 8 pad), 16B aligned
#define VSTR 72     // sV row stride in halves (64 + 8 pad), 16B aligned
#define PSTR 72     // sP row stride in halves

#define LOG2E 1.44269504088896f

typedef _Float16 h8 __attribute__((ext_vector_type(8)));
typedef _Float16 h4 __attribute__((ext_vector_type(4)));
typedef float    f4 __attribute__((ext_vector_type(4)));

// Flash sliding-window attention, GQA 16q/8kv, d=128, window=1024 (incl. self).
// MFMA 16x16x32 f16, swapped operands: lane owns one q-row (q=ln).
// R2 changes vs R1 (latency-bound: MfmaUtil 8.5%, VALUBusy 16%, all pipes idle):
//  - T14 async-stage: issue tile t+1 global loads after the post-write barrier,
//    convert+write them NEXT iteration -> staging latency hidden under compute.
//  - kb/vb fragments hoisted across the two q-stripes (ct-outer QK, ks-outer PV)
//    -> LDS b128 reads per wave-tile 68 -> 36.
//  - sP doubled per stripe -> WAR lgkm drain gone (tile barriers cover it);
//    single RAW drain per tile instead of 4 full drains.
// NOTE: __launch_bounds__(256,2) — (256,3) forces VGPR cap 84 -> ~1.1 GB spill
// traffic per launch (prev session R2). Do not raise.
__global__ __launch_bounds__(256, 2)
void fa_swa_kernel(const float* __restrict__ Qg, const float* __restrict__ Kg,
                   const float* __restrict__ Vg, float* __restrict__ Og) {
  __shared__ _Float16 sK[KT * KSTR];            // [s][dd] fp16        17408 B
  __shared__ _Float16 sV[HD * VSTR];            // [dd][s] fp16 (T)    18432 B
  __shared__ _Float16 sP[4][2 * 16 * PSTR];     // per-wave, per-stripe 18432 B -> 53 KB

  const int tid  = threadIdx.x;
  const int w    = tid >> 6;
  const int lane = tid & 63;
  const int quad = lane >> 4;
  const int ln   = lane & 15;

  const int qt = blockIdx.x;
  const int h  = blockIdx.y;
  const int bz = blockIdx.z;
  const int hk = h >> 1;
  const int q0 = qt * QT;

  // ---- Q fragments in registers (A/B-layout), fp32 -> fp16, pre-scaled by
  // log2(e) so softmax runs directly on v_exp_f32 (exp2 domain) ----
  h8 qf[2][4];
  #pragma unroll
  for (int r = 0; r < 2; ++r) {
    const int qg = q0 + w * 32 + r * 16 + ln;
    const float* qp = Qg + ((size_t)((size_t)bz * TSEQ + qg) * NQH + h) * HD + quad * 8;
    #pragma unroll
    for (int ks = 0; ks < 4; ++ks) {
      f4 a = *(const f4*)(qp + ks * 32);
      f4 b = *(const f4*)(qp + ks * 32 + 4);
      h8 qv;
      qv[0] = (_Float16)(a[0] * LOG2E); qv[1] = (_Float16)(a[1] * LOG2E);
      qv[2] = (_Float16)(a[2] * LOG2E); qv[3] = (_Float16)(a[3] * LOG2E);
      qv[4] = (_Float16)(b[0] * LOG2E); qv[5] = (_Float16)(b[1] * LOG2E);
      qv[6] = (_Float16)(b[2] * LOG2E); qv[7] = (_Float16)(b[3] * LOG2E);
      qf[r][ks] = qv;
    }
  }

  f4 Oacc[2][8];
  #pragma unroll
  for (int r = 0; r < 2; ++r)
    #pragma unroll
    for (int c = 0; c < 8; ++c)
      Oacc[r][c] = (f4){0.f, 0.f, 0.f, 0.f};

  float mrow[2] = {-INFINITY, -INFINITY};
  float lrow[2] = {0.f, 0.f};

  int s_begin = q0 - WINSZ; if (s_begin < 0) s_begin = 0;   // multiple of 64
  const int s_end = q0 + QT;

  const float* kbase = Kg + ((size_t)((size_t)bz * TSEQ) * NKVH + hk) * HD;
  const float* vbase = Vg + ((size_t)((size_t)bz * TSEQ) * NKVH + hk) * HD;

  const int srow = tid & 63;          // V staging row within tile
  const int dd0  = (tid >> 6) * 32;   // V staging dd base

  // ---- prefetch registers (tile t+1 in flight during compute of tile t) ----
  f4 kpre[8], vpre[8];

  #define ISSUE_LOADS(S0)                                                       \
    {                                                                           \
      const float* kp = kbase + (size_t)(S0) * (NKVH * HD);                     \
      _Pragma("unroll")                                                         \
      for (int i = 0; i < 8; ++i) {                                             \
        int e   = tid + 256 * i;                                                \
        int row = e >> 5;                                                       \
        int c4  = (e & 31) * 4;                                                 \
        kpre[i] = *(const f4*)(kp + (size_t)row * (NKVH * HD) + c4);            \
      }                                                                         \
      const float* vp = vbase + (size_t)((S0) + srow) * (NKVH * HD) + dd0;      \
      _Pragma("unroll")                                                         \
      for (int f = 0; f < 8; ++f) vpre[f] = *(const f4*)(vp + f * 4);           \
    }

  ISSUE_LOADS(s_begin);

  for (int s0 = s_begin; s0 < s_end; s0 += KT) {
    __syncthreads();   // barrier1: all waves done reading sK/sV of prev tile;
                       // also retires prev tile's pa reads (lgkm drained here)

    // ---- write staged tile from prefetch regs (loads landed during compute) ----
    #pragma unroll
    for (int i = 0; i < 8; ++i) {
      int e   = tid + 256 * i;
      int row = e >> 5;
      int c4  = (e & 31) * 4;
      f4 x = kpre[i];
      h4 hv;
      hv[0] = (_Float16)x[0]; hv[1] = (_Float16)x[1];
      hv[2] = (_Float16)x[2]; hv[3] = (_Float16)x[3];
      *(h4*)(&sK[row * KSTR + c4]) = hv;
    }
    #pragma unroll
    for (int f = 0; f < 8; ++f) {
      f4 x = vpre[f];
      #pragma unroll
      for (int c = 0; c < 4; ++c)
        sV[(dd0 + f * 4 + c) * VSTR + srow] = (_Float16)x[c];
    }
    __syncthreads();   // barrier2: tile visible (lgkm-only drain, cheap)

    // ---- issue next tile's global loads; latency hides under compute ----
    if (s0 + KT < s_end) ISSUE_LOADS(s0 + KT);

    const int  dq0 = q0 + w * 32 - s0;
    const int  dq1 = dq0 + 16;
    const bool a0  = (dq0 >= 0) && (dq0 <= 1072);
    const bool a1  = (dq1 >= 0) && (dq1 <= 1072);
    if (!(a0 || a1)) continue;

    // ---- QK: ct-outer so kb fragments are shared across both stripes ----
    f4 S[2][4];
    #pragma unroll
    for (int ct = 0; ct < 4; ++ct) {
      f4 acc0 = (f4){0.f, 0.f, 0.f, 0.f};
      f4 acc1 = (f4){0.f, 0.f, 0.f, 0.f};
      #pragma unroll
      for (int ks = 0; ks < 4; ++ks) {
        h8 kb = *(const h8*)(&sK[(ct * 16 + ln) * KSTR + quad * 8 + ks * 32]);
        if (a0) acc0 = __builtin_amdgcn_mfma_f32_16x16x32_f16(kb, qf[0][ks], acc0, 0, 0, 0);
        if (a1) acc1 = __builtin_amdgcn_mfma_f32_16x16x32_f16(kb, qf[1][ks], acc1, 0, 0, 0);
      }
      S[0][ct] = acc0;
      S[1][ct] = acc1;
    }

    // ---- mask + online softmax per stripe; stage P for both stripes ----
    #pragma unroll
    for (int r = 0; r < 2; ++r) {
      const bool act = (r == 0) ? a0 : a1;
      if (!act) continue;
      const int dq = dq0 + r * 16;

      if (dq < 64 || dq > 1008) {
        const int e = dq + ln - quad * 4;   // q - key = e - ct*16 - g
        #pragma unroll
        for (int ct = 0; ct < 4; ++ct) {
          const int base = e - ct * 16;
          #pragma unroll
          for (int g = 0; g < 4; ++g)
            if ((unsigned)(base - g) > 1023u) S[r][ct][g] = -INFINITY;
        }
      }

      float m = -INFINITY;
      #pragma unroll
      for (int ct = 0; ct < 4; ++ct)
        m = fmaxf(m, fmaxf(fmaxf(S[r][ct][0], S[r][ct][1]),
                           fmaxf(S[r][ct][2], S[r][ct][3])));
      m = fmaxf(m, __shfl_xor(m, 16));
      m = fmaxf(m, __shfl_xor(m, 32));
      const float mn  = fmaxf(mrow[r], m);
      const bool dead = (mn == -INFINITY);
      const float al  = dead ? 1.f : __builtin_amdgcn_exp2f(mrow[r] - mn);
      mrow[r] = mn;

      float ps = 0.f;
      #pragma unroll
      for (int ct = 0; ct < 4; ++ct)
        #pragma unroll
        for (int g = 0; g < 4; ++g) {
          float p = dead ? 0.f : __builtin_amdgcn_exp2f(S[r][ct][g] - mn);
          S[r][ct][g] = p;
          ps += p;
        }
      ps += __shfl_xor(ps, 16);
      ps += __shfl_xor(ps, 32);
      lrow[r] = lrow[r] * al + ps;

      #pragma unroll
      for (int ct = 0; ct < 8; ++ct)
        #pragma unroll
        for (int g = 0; g < 4; ++g)
          Oacc[r][ct][g] *= al;

      // P -> per-stripe sP region (contiguous h4); WAR vs last tile's pa reads
      // is covered by barrier1's lgkm drain.
      #pragma unroll
      for (int ct = 0; ct < 4; ++ct) {
        h4 pv;
        pv[0] = (_Float16)S[r][ct][0]; pv[1] = (_Float16)S[r][ct][1];
        pv[2] = (_Float16)S[r][ct][2]; pv[3] = (_Float16)S[r][ct][3];
        *(h4*)(&sP[w][(r * 16 + ln) * PSTR + ct * 16 + quad * 4]) = pv;
      }
    }

    __asm__ volatile("s_waitcnt lgkmcnt(0)" ::: "memory");  // sP RAW (wave-private)

    // ---- PV: ks-outer so vb fragments are shared across both stripes ----
    #pragma unroll
    for (int ks = 0; ks < 2; ++ks) {
      h8 pa0 = {}, pa1 = {};
      if (a0) pa0 = *(const h8*)(&sP[w][(0 * 16 + ln) * PSTR + quad * 8 + ks * 32]);
      if (a1) pa1 = *(const h8*)(&sP[w][(1 * 16 + ln) * PSTR + quad * 8 + ks * 32]);
      #pragma unroll
      for (int ct = 0; ct < 8; ++ct) {
        h8 vb = *(const h8*)(&sV[(ct * 16 + ln) * VSTR + quad * 8 + ks * 32]);
        if (a0) Oacc[0][ct] = __builtin_amdgcn_mfma_f32_16x16x32_f16(vb, pa0, Oacc[0][ct], 0, 0, 0);
        if (a1) Oacc[1][ct] = __builtin_amdgcn_mfma_f32_16x16x32_f16(vb, pa1, Oacc[1][ct], 0, 0, 0);
      }
    }
  }

  // ---- epilogue: O / l, vectorized f4 stores (q = ln, d = ct*16+quad*4+g) ----
  #pragma unroll
  for (int r = 0; r < 2; ++r) {
    const int qg = q0 + w * 32 + r * 16 + ln;
    const float inv = 1.f / lrow[r];
    float* op = Og + ((size_t)((size_t)bz * TSEQ + qg) * NQH + h) * HD + quad * 4;
    #pragma unroll
    for (int ct = 0; ct < 8; ++ct) {
      f4 o;
      o[0] = Oacc[r][ct][0] * inv; o[1] = Oacc[r][ct][1] * inv;
      o[2] = Oacc[r][ct][2] * inv; o[3] = Oacc[r][ct][3] * inv;
      *(f4*)(op + ct * 16) = o;
    }
  }
}

extern "C" void kernel_launch(void* const* d_in, const int* in_sizes, int n_in,
                              void* d_out, int out_size, void* d_ws, size_t ws_size,
                              hipStream_t stream) {
  const float* Q = (const float*)d_in[0];
  const float* K = (const float*)d_in[1];
  const float* V = (const float*)d_in[2];
  float* O = (float*)d_out;
  const int batch = in_sizes[0] / (TSEQ * NQH * HD);   // 4
  dim3 grid(TSEQ / QT, NQH, batch);
  fa_swa_kernel<<<grid, 256, 0, stream>>>(Q, K, V, O);
}